// Round 5
// baseline (425.805 us; speedup 1.0000x reference)
//
#include <hip/hip_runtime.h>

// Problem constants
#define TT 8
#define WQ 75
#define CC 64
#define HW 441
#define WAY 5
#define SHOT 5
#define NSAMP 2205     // SHOT*HW
#define NEG 0.2f

// ws layout (floats):
//   Wfinal : 40  * 4096            = 163840
//   pG     : 400 * 4096            = 1638400   (2 position-halves per (t,s))
//   pS     : 400 * 64              = 25600
// total = 1827840 floats = 7.31 MB

// ---------------------------------------------------------------------------
// Kernel 1: per-(t,shot,half) partial second moment G = X X^T and column sums.
// X is [64][441] contiguous. 400 blocks ((t*25+s)*2+half), 256 threads.
// half 0: chunks 0..6 (pos 0..223), half 1: chunks 7..13 (pos 224..440).
// ---------------------------------------------------------------------------
__global__ __launch_bounds__(256) void k_partial(const float* __restrict__ sup,
                                                 float* __restrict__ pG,
                                                 float* __restrict__ pS) {
    const int blk = blockIdx.x;                  // (t*25+s)*2 + half
    const int half = blk & 1;
    const int b = blk >> 1;                      // t*25 + s
    const float* __restrict__ X = sup + (size_t)b * CC * HW;
    __shared__ float lds[32 * 68];               // [pp][c], stride 68 words
    const int tid = threadIdx.x;
    const int i = tid & 15;                      // c-tile index
    const int j = tid >> 4;                      // d-tile index
    const int c0 = half * 7, c1 = c0 + 7;        // chunk range

    float acc[4][4];
#pragma unroll
    for (int a = 0; a < 4; ++a)
#pragma unroll
        for (int bb = 0; bb < 4; ++bb) acc[a][bb] = 0.f;
    float cs = 0.f;                              // column sum for c==tid (tid<64)

    float ld[8];
    // prologue: load first chunk
#pragma unroll
    for (int k = 0; k < 8; ++k) {
        const int e = tid + k * 256;
        const int r = e >> 5, pp = e & 31;
        const int p = c0 * 32 + pp;
        ld[k] = (p < HW) ? X[r * HW + p] : 0.f;
    }

    for (int chunk = c0; chunk < c1; ++chunk) {
        __syncthreads();                         // LDS free from previous compute
#pragma unroll
        for (int k = 0; k < 8; ++k) {
            const int e = tid + k * 256;
            const int r = e >> 5, pp = e & 31;
            lds[pp * 68 + r] = ld[k];
        }
        // prefetch next chunk while this one is being consumed
        float ld2[8];
        if (chunk + 1 < c1) {
            const int p0 = (chunk + 1) * 32;
#pragma unroll
            for (int k = 0; k < 8; ++k) {
                const int e = tid + k * 256;
                const int r = e >> 5, pp = e & 31;
                const int p = p0 + pp;
                ld2[k] = (p < HW) ? X[r * HW + p] : 0.f;
            }
        } else {
#pragma unroll
            for (int k = 0; k < 8; ++k) ld2[k] = 0.f;
        }
        __syncthreads();
#pragma unroll 4
        for (int pp = 0; pp < 32; ++pp) {
            const float* row = &lds[pp * 68];
            const float a0 = row[4 * i + 0], a1 = row[4 * i + 1],
                        a2 = row[4 * i + 2], a3 = row[4 * i + 3];
            const float b0 = row[4 * j + 0], b1 = row[4 * j + 1],
                        b2 = row[4 * j + 2], b3 = row[4 * j + 3];
            acc[0][0] += a0 * b0; acc[0][1] += a0 * b1; acc[0][2] += a0 * b2; acc[0][3] += a0 * b3;
            acc[1][0] += a1 * b0; acc[1][1] += a1 * b1; acc[1][2] += a1 * b2; acc[1][3] += a1 * b3;
            acc[2][0] += a2 * b0; acc[2][1] += a2 * b1; acc[2][2] += a2 * b2; acc[2][3] += a2 * b3;
            acc[3][0] += a3 * b0; acc[3][1] += a3 * b1; acc[3][2] += a3 * b2; acc[3][3] += a3 * b3;
        }
        if (tid < CC) {
#pragma unroll 8
            for (int pp = 0; pp < 32; ++pp) cs += lds[pp * 68 + tid];
        }
#pragma unroll
        for (int k = 0; k < 8; ++k) ld[k] = ld2[k];
    }

    float* __restrict__ G = pG + (size_t)blk * 4096;
#pragma unroll
    for (int a = 0; a < 4; ++a)
#pragma unroll
        for (int bb = 0; bb < 4; ++bb)
            G[(4 * i + a) * 64 + (4 * j + bb)] = acc[a][bb];
    if (tid < CC) pS[blk * 64 + tid] = cs;
}

// ---------------------------------------------------------------------------
// Kernel 1b: reduce 10 partials (5 shots x 2 halves) -> covariance -> W
// (upper-tri, off-diag doubled, zeros below). 40 blocks, 256 threads.
// ---------------------------------------------------------------------------
__global__ __launch_bounds__(256) void k_finalize(const float* __restrict__ pG,
                                                  const float* __restrict__ pS,
                                                  float* __restrict__ W) {
    const int b = blockIdx.x;                    // t*5 + way
    const int t = b / WAY, way = b % WAY;
    const int s0 = (t * 25 + way * SHOT) * 2;    // first partial index
    float* __restrict__ Wm = W + (size_t)b * 4096;

    for (int idx = threadIdx.x; idx < 4096; idx += 256) {
        const int c = idx >> 6, d = idx & 63;
        if (d < c) continue;                     // owner of pair (c,d) writes both
        float g = 0.f, Sc = 0.f, Sd = 0.f;
#pragma unroll
        for (int s = 0; s < SHOT * 2; ++s) {
            g  += pG[(size_t)(s0 + s) * 4096 + idx];
            Sc += pS[(s0 + s) * 64 + c];
            Sd += pS[(s0 + s) * 64 + d];
        }
        const float cov = (g - Sc * Sd * (1.f / NSAMP)) * (1.f / (HW - 1));
        if (d == c) {
            Wm[idx] = cov;
        } else {
            Wm[c * 64 + d] = 2.f * cov;
            Wm[d * 64 + c] = 0.f;
        }
    }
}

// ---------------------------------------------------------------------------
// Kernel 2 v4: one (t,q) per block, runtime way-loop (I$-friendly: the 2080-FMA
// body appears ONCE). __launch_bounds__(448,1) gives the allocator a full VGPR
// budget so q[64] lives in architectural VGPRs, not AGPR copies (v3: VGPR=60,
// AGPR shuffling made VALU 3x the FMA floor).
// ---------------------------------------------------------------------------
__global__ __launch_bounds__(448, 1) void k_sim(const float* __restrict__ Q,
                                                const float* __restrict__ W,
                                                const float* __restrict__ cw,
                                                const float* __restrict__ cb,
                                                float* __restrict__ out) {
    const int b = blockIdx.x;                    // t*75 + q
    const int t = b / WQ;
    const int tid = threadIdx.x;
    const int lane = tid & 63;
    const int wave = tid >> 6;                   // 0..6
    const int p = tid;
    const float validf = (p < HW) ? 1.f : 0.f;
    const int pc = (p < HW) ? p : (HW - 1);

    const float* __restrict__ Qb = Q + (size_t)b * CC * HW;

    float q[CC];
#pragma unroll
    for (int c = 0; c < CC; ++c) q[c] = Qb[c * HW + pc] * validf;

    __shared__ float red[CC * 9];
    __shared__ float mu[CC];
    __shared__ float fin[8];

    // block-wide per-channel mean over 441 valid positions
#pragma unroll
    for (int c = 0; c < CC; ++c) {
        float v = q[c];
#pragma unroll
        for (int m = 32; m > 0; m >>= 1) v += __shfl_xor(v, m, 64);
        if (lane == 0) red[c * 9 + wave] = v;
    }
    __syncthreads();
    if (tid < CC) {
        float s = 0.f;
#pragma unroll
        for (int w2 = 0; w2 < 7; ++w2) s += red[tid * 9 + w2];
        mu[tid] = s * (1.f / HW);
    }
    __syncthreads();
#pragma unroll
    for (int c = 0; c < CC; ++c) {
        q[c] -= mu[c];
        asm volatile("" : "+v"(q[c]));           // pin: no remat, no reload
    }

    const float cwp = cw[pc] * validf;
    const float* __restrict__ Wbase = W + (size_t)t * WAY * 4096;

#pragma unroll 1
    for (int w = 0; w < WAY; ++w) {              // runtime loop: body once in I$
        const float* __restrict__ Wm = Wbase + w * 4096;
        float sim = 0.f;
#pragma unroll
        for (int c = 0; c < CC; ++c) {
            const float* __restrict__ row = Wm + c * 64;
            float t0 = 0.f, t1 = 0.f, t2 = 0.f, t3 = 0.f;
            const int dstart = c & ~3;           // aligned start; W below diag is 0
#pragma unroll
            for (int d = dstart; d < CC; d += 4) {
                t0 += row[d + 0] * q[d + 0];
                t1 += row[d + 1] * q[d + 1];
                t2 += row[d + 2] * q[d + 2];
                t3 += row[d + 3] * q[d + 3];
            }
            sim += q[c] * ((t0 + t1) + (t2 + t3));
        }
        // LeakyReLU then weighted reduction with conv_w
        const float x = (sim >= 0.f) ? sim : NEG * sim;
        float contrib = x * cwp;
#pragma unroll
        for (int m = 32; m > 0; m >>= 1) contrib += __shfl_xor(contrib, m, 64);
        if (lane == 0) fin[wave] = contrib;
        __syncthreads();
        if (tid == 0) {
            float s = 0.f;
#pragma unroll
            for (int w2 = 0; w2 < 7; ++w2) s += fin[w2];
            out[b * WAY + w] = s + cb[0];
        }
        __syncthreads();                         // protect fin before next way
    }
}

// ---------------------------------------------------------------------------
extern "C" void kernel_launch(void* const* d_in, const int* in_sizes, int n_in,
                              void* d_out, int out_size, void* d_ws, size_t ws_size,
                              hipStream_t stream) {
    const float* q   = (const float*)d_in[0];   // (8,75,64,21,21)
    const float* sup = (const float*)d_in[1];   // (8,25,64,21,21)
    const float* cw  = (const float*)d_in[2];   // (441,)
    const float* cb  = (const float*)d_in[3];   // (1,)
    float* out = (float*)d_out;                  // (8,75,5)

    float* wsf  = (float*)d_ws;
    float* Wbuf = wsf;                           // 163840 floats
    float* pG   = wsf + 163840;                  // 1638400 floats
    float* pS   = wsf + 163840 + 1638400;        // 25600 floats

    k_partial<<<TT * 25 * 2, 256, 0, stream>>>(sup, pG, pS);
    k_finalize<<<TT * WAY, 256, 0, stream>>>(pG, pS, Wbuf);
    k_sim<<<TT * WQ, 448, 0, stream>>>(q, Wbuf, cw, cb, out);
}

// Round 7
// 416.294 us; speedup vs baseline: 1.0228x; 1.0228x over previous
//
#include <hip/hip_runtime.h>

// Problem constants
#define TT 8
#define WQ 75
#define CC 64
#define HW 441
#define WAY 5
#define SHOT 5
#define NSAMP 2205     // SHOT*HW
#define NEG 0.2f
#define PPAD 448       // padded positions

typedef __attribute__((ext_vector_type(8))) short bf16x8;
typedef __attribute__((ext_vector_type(4))) float f32x4;

__device__ inline unsigned short f2bf(float f) {
    unsigned u = __float_as_uint(f);
    u += 0x7FFFu + ((u >> 16) & 1u);
    return (unsigned short)(u >> 16);
}
__device__ inline float bf2f(unsigned us) {
    return __uint_as_float((us & 0xFFFFu) << 16);
}

// ---------------------------------------------------------------------------
// Kernel 1: per-(t,shot,half) partial second moment G = X X^T and column sums.
// 400 blocks ((t*25+s)*2+half), 256 threads.
// ---------------------------------------------------------------------------
__global__ __launch_bounds__(256) void k_partial(const float* __restrict__ sup,
                                                 float* __restrict__ pG,
                                                 float* __restrict__ pS) {
    const int blk = blockIdx.x;
    const int half = blk & 1;
    const int b = blk >> 1;                      // t*25 + s
    const float* __restrict__ X = sup + (size_t)b * CC * HW;
    __shared__ float lds[32 * 68];
    const int tid = threadIdx.x;
    const int i = tid & 15;
    const int j = tid >> 4;
    const int c0 = half * 7, c1 = c0 + 7;

    float acc[4][4];
#pragma unroll
    for (int a = 0; a < 4; ++a)
#pragma unroll
        for (int bb = 0; bb < 4; ++bb) acc[a][bb] = 0.f;
    float cs = 0.f;

    float ld[8];
#pragma unroll
    for (int k = 0; k < 8; ++k) {
        const int e = tid + k * 256;
        const int r = e >> 5, pp = e & 31;
        const int p = c0 * 32 + pp;
        ld[k] = (p < HW) ? X[r * HW + p] : 0.f;
    }

    for (int chunk = c0; chunk < c1; ++chunk) {
        __syncthreads();
#pragma unroll
        for (int k = 0; k < 8; ++k) {
            const int e = tid + k * 256;
            const int r = e >> 5, pp = e & 31;
            lds[pp * 68 + r] = ld[k];
        }
        float ld2[8];
        if (chunk + 1 < c1) {
            const int p0 = (chunk + 1) * 32;
#pragma unroll
            for (int k = 0; k < 8; ++k) {
                const int e = tid + k * 256;
                const int r = e >> 5, pp = e & 31;
                const int p = p0 + pp;
                ld2[k] = (p < HW) ? X[r * HW + p] : 0.f;
            }
        } else {
#pragma unroll
            for (int k = 0; k < 8; ++k) ld2[k] = 0.f;
        }
        __syncthreads();
#pragma unroll 4
        for (int pp = 0; pp < 32; ++pp) {
            const float* row = &lds[pp * 68];
            const float a0 = row[4 * i + 0], a1 = row[4 * i + 1],
                        a2 = row[4 * i + 2], a3 = row[4 * i + 3];
            const float b0 = row[4 * j + 0], b1 = row[4 * j + 1],
                        b2 = row[4 * j + 2], b3 = row[4 * j + 3];
            acc[0][0] += a0 * b0; acc[0][1] += a0 * b1; acc[0][2] += a0 * b2; acc[0][3] += a0 * b3;
            acc[1][0] += a1 * b0; acc[1][1] += a1 * b1; acc[1][2] += a1 * b2; acc[1][3] += a1 * b3;
            acc[2][0] += a2 * b0; acc[2][1] += a2 * b1; acc[2][2] += a2 * b2; acc[2][3] += a2 * b3;
            acc[3][0] += a3 * b0; acc[3][1] += a3 * b1; acc[3][2] += a3 * b2; acc[3][3] += a3 * b3;
        }
        if (tid < CC) {
#pragma unroll 8
            for (int pp = 0; pp < 32; ++pp) cs += lds[pp * 68 + tid];
        }
#pragma unroll
        for (int k = 0; k < 8; ++k) ld[k] = ld2[k];
    }

    float* __restrict__ G = pG + (size_t)blk * 4096;
#pragma unroll
    for (int a = 0; a < 4; ++a)
#pragma unroll
        for (int bb = 0; bb < 4; ++bb)
            G[(4 * i + a) * 64 + (4 * j + bb)] = acc[a][bb];
    if (tid < CC) pS[blk * 64 + tid] = cs;
}

// ---------------------------------------------------------------------------
// Kernel 1b: reduce 10 partials -> covariance -> FULL symmetric W in bf16
// hi/lo split. 40 blocks, 256 threads.
// ---------------------------------------------------------------------------
__global__ __launch_bounds__(256) void k_finalize(const float* __restrict__ pG,
                                                  const float* __restrict__ pS,
                                                  unsigned short* __restrict__ Wh,
                                                  unsigned short* __restrict__ Wl) {
    const int b = blockIdx.x;                    // t*5 + way
    const int t = b / WAY, way = b % WAY;
    const int s0 = (t * 25 + way * SHOT) * 2;

    for (int idx = threadIdx.x; idx < 4096; idx += 256) {
        const int c = idx >> 6, d = idx & 63;
        float g = 0.f, Sc = 0.f, Sd = 0.f;
#pragma unroll
        for (int s = 0; s < SHOT * 2; ++s) {
            g  += pG[(size_t)(s0 + s) * 4096 + idx];
            Sc += pS[(s0 + s) * 64 + c];
            Sd += pS[(s0 + s) * 64 + d];
        }
        const float cov = (g - Sc * Sd * (1.f / NSAMP)) * (1.f / (HW - 1));
        const unsigned short hi = f2bf(cov);
        const unsigned short lo = f2bf(cov - bf2f(hi));
        Wh[(size_t)b * 4096 + idx] = hi;
        Wl[(size_t)b * 4096 + idx] = lo;
    }
}

// ---------------------------------------------------------------------------
// Kernel 1c: per-(t,qi) channel means, center Q, split to bf16 hi/lo in
// TRANSPOSED [pos][ch] layout (so MFMA B-frags are contiguous dwordx4).
// 600 blocks, 256 threads.
// ---------------------------------------------------------------------------
__global__ __launch_bounds__(256) void k_center(const float* __restrict__ Q,
                                                unsigned short* __restrict__ Sh,
                                                unsigned short* __restrict__ Sl) {
    const int b = blockIdx.x;                    // t*75 + qi
    const float* __restrict__ Qb = Q + (size_t)b * CC * HW;
    const int tid = threadIdx.x;
    __shared__ float part[CC][4];
    __shared__ float mu[CC];

    // pass 1: per-channel mean (c = tid>>2, quarter = tid&3)
    {
        const int c = tid >> 2, qtr = tid & 3;
        float s = 0.f;
        for (int p = qtr; p < HW; p += 4) s += Qb[(size_t)c * HW + p];
        part[c][qtr] = s;
    }
    __syncthreads();
    if (tid < CC) mu[tid] = (part[tid][0] + part[tid][1] + part[tid][2] + part[tid][3]) * (1.f / HW);
    __syncthreads();

    // pass 2: center + split + transpose-store
    for (int p = tid; p < PPAD; p += 256) {
        const bool pv = (p < HW);
        const size_t obase = ((size_t)b * PPAD + p) * CC;
#pragma unroll
        for (int o = 0; o < 8; ++o) {
            unsigned hpack[4], lpack[4];
#pragma unroll
            for (int jj = 0; jj < 4; ++jj) {
                const int cA = o * 8 + jj * 2;
                const float v0 = pv ? (Qb[(size_t)cA * HW + p] - mu[cA]) : 0.f;
                const float v1 = pv ? (Qb[(size_t)(cA + 1) * HW + p] - mu[cA + 1]) : 0.f;
                const unsigned short h0 = f2bf(v0), h1 = f2bf(v1);
                const unsigned short l0 = f2bf(v0 - bf2f(h0)), l1 = f2bf(v1 - bf2f(h1));
                hpack[jj] = (unsigned)h0 | ((unsigned)h1 << 16);
                lpack[jj] = (unsigned)l0 | ((unsigned)l1 << 16);
            }
            *(uint4*)(Sh + obase + o * 8) = make_uint4(hpack[0], hpack[1], hpack[2], hpack[3]);
            *(uint4*)(Sl + obase + o * 8) = make_uint4(lpack[0], lpack[1], lpack[2], lpack[3]);
        }
    }
}

// ---------------------------------------------------------------------------
// Kernel 2 v5: split-bf16 MFMA. Block = (t,qi), 4 waves. Wave owns p-tiles
// {wid+4k}. Per way: W-frags (hi/lo) in regs; per p-tile: B-frags direct from
// global; 24x mfma_f32_16x16x32_bf16; fp32 epilogue (S=hi+lo), lrelu, cw-dot.
// No LDS in main loop, one barrier at the end.
// ---------------------------------------------------------------------------
__global__ __launch_bounds__(256) void k_sim(const unsigned short* __restrict__ Sh,
                                             const unsigned short* __restrict__ Sl,
                                             const unsigned short* __restrict__ Wh,
                                             const unsigned short* __restrict__ Wl,
                                             const float* __restrict__ cw,
                                             const float* __restrict__ cb,
                                             float* __restrict__ out) {
    const int b = blockIdx.x;                    // t*75 + qi
    const int t = b / WQ;
    const int tid = threadIdx.x;
    const int lane = tid & 63;
    const int wid = tid >> 6;                    // 0..3
    const int lm16 = lane & 15;
    const int l16 = lane >> 4;                   // 0..3
    const float lanemask = (l16 == 0) ? 1.f : 0.f;

    __shared__ float fin[WAY][4];

    const size_t sbase = (size_t)b * PPAD * CC;

#pragma unroll 1
    for (int w = 0; w < WAY; ++w) {
        const unsigned short* __restrict__ Wm_h = Wh + (size_t)(t * WAY + w) * 4096;
        const unsigned short* __restrict__ Wm_l = Wl + (size_t)(t * WAY + w) * 4096;

        // A-frags: A[r][k], r = rt*16 + (lane&15), k = ks*32 + 8*(lane>>4) + i
        bf16x8 ah[4][2], al[4][2];
#pragma unroll
        for (int rt = 0; rt < 4; ++rt)
#pragma unroll
            for (int ks = 0; ks < 2; ++ks) {
                const size_t off = (size_t)(rt * 16 + lm16) * 64 + ks * 32 + 8 * l16;
                uint4 rh = *(const uint4*)(Wm_h + off);
                uint4 rl = *(const uint4*)(Wm_l + off);
                ah[rt][ks] = __builtin_bit_cast(bf16x8, rh);
                al[rt][ks] = __builtin_bit_cast(bf16x8, rl);
            }

        float wayacc = 0.f;
#pragma unroll 1
        for (int k = 0; k < 7; ++k) {
            const int p0 = (wid + 4 * k) * 16;
            const int p_l = p0 + lm16;

            // B-frags: B[k][col], col = lane&15 -> p, k = ks*32 + 8*(lane>>4)+i
            bf16x8 bh[2], bl[2];
#pragma unroll
            for (int ks = 0; ks < 2; ++ks) {
                const size_t off = sbase + (size_t)p_l * CC + ks * 32 + 8 * l16;
                uint4 rh = *(const uint4*)(Sh + off);
                uint4 rl = *(const uint4*)(Sl + off);
                bh[ks] = __builtin_bit_cast(bf16x8, rh);
                bl[ks] = __builtin_bit_cast(bf16x8, rl);
            }

            f32x4 acc[4];
#pragma unroll
            for (int rt = 0; rt < 4; ++rt) acc[rt] = (f32x4){0.f, 0.f, 0.f, 0.f};

#pragma unroll
            for (int rt = 0; rt < 4; ++rt)
#pragma unroll
                for (int ks = 0; ks < 2; ++ks) {
                    acc[rt] = __builtin_amdgcn_mfma_f32_16x16x32_bf16(ah[rt][ks], bh[ks], acc[rt], 0, 0, 0);
                    acc[rt] = __builtin_amdgcn_mfma_f32_16x16x32_bf16(ah[rt][ks], bl[ks], acc[rt], 0, 0, 0);
                    acc[rt] = __builtin_amdgcn_mfma_f32_16x16x32_bf16(al[rt][ks], bh[ks], acc[rt], 0, 0, 0);
                }

            // epilogue: sim partial = sum_c S[c][p]*M[c][p] over this lane's
            // 16 c's (c = rt*16 + 4*(lane>>4) + r), p = p0 + (lane&15)
            float simp = 0.f;
#pragma unroll
            for (int rt = 0; rt < 4; ++rt) {
                const size_t sb = sbase + (size_t)p_l * CC + rt * 16 + l16 * 4;
                uint2 hr = *(const uint2*)(Sh + sb);
                uint2 lr = *(const uint2*)(Sl + sb);
                const float s0 = bf2f(hr.x) + bf2f(lr.x);
                const float s1 = bf2f(hr.x >> 16) + bf2f(lr.x >> 16);
                const float s2 = bf2f(hr.y) + bf2f(lr.y);
                const float s3 = bf2f(hr.y >> 16) + bf2f(lr.y >> 16);
                simp += acc[rt].x * s0 + acc[rt].y * s1 + acc[rt].z * s2 + acc[rt].w * s3;
            }
            // combine the 4 row-quarter partials for this p
            simp += __shfl_xor(simp, 16, 64);
            simp += __shfl_xor(simp, 32, 64);

            const float cwv = (p_l < HW) ? cw[p_l] : 0.f;
            const float x = (simp >= 0.f) ? simp : NEG * simp;
            wayacc += lanemask * x * cwv;
        }

        // reduce wayacc across the wave (lanes >=16 contributed 0)
#pragma unroll
        for (int m = 32; m > 0; m >>= 1) wayacc += __shfl_xor(wayacc, m, 64);
        if (lane == 0) fin[w][wid] = wayacc;
    }

    __syncthreads();
    if (tid < WAY) {
        out[(size_t)b * WAY + tid] =
            fin[tid][0] + fin[tid][1] + fin[tid][2] + fin[tid][3] + cb[0];
    }
}

// ---------------------------------------------------------------------------
extern "C" void kernel_launch(void* const* d_in, const int* in_sizes, int n_in,
                              void* d_out, int out_size, void* d_ws, size_t ws_size,
                              hipStream_t stream) {
    const float* q   = (const float*)d_in[0];   // (8,75,64,21,21)
    const float* sup = (const float*)d_in[1];   // (8,25,64,21,21)
    const float* cw  = (const float*)d_in[2];   // (441,)
    const float* cb  = (const float*)d_in[3];   // (1,)
    float* out = (float*)d_out;                  // (8,75,5)

    char* ws = (char*)d_ws;
    float* pG = (float*)ws;                                    //  6,553,600 B
    float* pS = (float*)(ws + 6553600);                        //    102,400 B
    unsigned short* Wh = (unsigned short*)(ws + 6656000);      //    327,680 B
    unsigned short* Wl = (unsigned short*)(ws + 6983680);      //    327,680 B
    unsigned short* Sh = (unsigned short*)(ws + 7311360);      // 34,406,400 B
    unsigned short* Sl = (unsigned short*)(ws + 41717760);     // 34,406,400 B
    // total 76,124,160 B

    k_partial<<<TT * 25 * 2, 256, 0, stream>>>(sup, pG, pS);
    k_finalize<<<TT * WAY, 256, 0, stream>>>(pG, pS, Wh, Wl);
    k_center<<<TT * WQ, 256, 0, stream>>>(q, Sh, Sl);
    k_sim<<<TT * WQ, 256, 0, stream>>>(Sh, Sl, Wh, Wl, cw, cb, out);
}

// Round 8
// 265.777 us; speedup vs baseline: 1.6021x; 1.5663x over previous
//
#include <hip/hip_runtime.h>

// Problem constants
#define TT 8
#define WQ 75
#define CC 64
#define HW 441
#define WAY 5
#define SHOT 5
#define NSAMP 2205     // SHOT*HW
#define NEG 0.2f

typedef __attribute__((ext_vector_type(8))) short bf16x8;
typedef __attribute__((ext_vector_type(4))) float f32x4;

__device__ inline unsigned short f2bf(float f) {
    unsigned u = __float_as_uint(f);
    u += 0x7FFFu + ((u >> 16) & 1u);
    return (unsigned short)(u >> 16);
}
__device__ inline float bf2f(unsigned us) {
    return __uint_as_float((us & 0xFFFFu) << 16);
}

// ---------------------------------------------------------------------------
// Kernel 1: per-(t,shot,half) partial second moment G = X X^T and column sums.
// 400 blocks ((t*25+s)*2+half), 256 threads. (verified in R7, unchanged)
// ---------------------------------------------------------------------------
__global__ __launch_bounds__(256) void k_partial(const float* __restrict__ sup,
                                                 float* __restrict__ pG,
                                                 float* __restrict__ pS) {
    const int blk = blockIdx.x;
    const int half = blk & 1;
    const int b = blk >> 1;                      // t*25 + s
    const float* __restrict__ X = sup + (size_t)b * CC * HW;
    __shared__ float lds[32 * 68];
    const int tid = threadIdx.x;
    const int i = tid & 15;
    const int j = tid >> 4;
    const int c0 = half * 7, c1 = c0 + 7;

    float acc[4][4];
#pragma unroll
    for (int a = 0; a < 4; ++a)
#pragma unroll
        for (int bb = 0; bb < 4; ++bb) acc[a][bb] = 0.f;
    float cs = 0.f;

    float ld[8];
#pragma unroll
    for (int k = 0; k < 8; ++k) {
        const int e = tid + k * 256;
        const int r = e >> 5, pp = e & 31;
        const int p = c0 * 32 + pp;
        ld[k] = (p < HW) ? X[r * HW + p] : 0.f;
    }

    for (int chunk = c0; chunk < c1; ++chunk) {
        __syncthreads();
#pragma unroll
        for (int k = 0; k < 8; ++k) {
            const int e = tid + k * 256;
            const int r = e >> 5, pp = e & 31;
            lds[pp * 68 + r] = ld[k];
        }
        float ld2[8];
        if (chunk + 1 < c1) {
            const int p0 = (chunk + 1) * 32;
#pragma unroll
            for (int k = 0; k < 8; ++k) {
                const int e = tid + k * 256;
                const int r = e >> 5, pp = e & 31;
                const int p = p0 + pp;
                ld2[k] = (p < HW) ? X[r * HW + p] : 0.f;
            }
        } else {
#pragma unroll
            for (int k = 0; k < 8; ++k) ld2[k] = 0.f;
        }
        __syncthreads();
#pragma unroll 4
        for (int pp = 0; pp < 32; ++pp) {
            const float* row = &lds[pp * 68];
            const float a0 = row[4 * i + 0], a1 = row[4 * i + 1],
                        a2 = row[4 * i + 2], a3 = row[4 * i + 3];
            const float b0 = row[4 * j + 0], b1 = row[4 * j + 1],
                        b2 = row[4 * j + 2], b3 = row[4 * j + 3];
            acc[0][0] += a0 * b0; acc[0][1] += a0 * b1; acc[0][2] += a0 * b2; acc[0][3] += a0 * b3;
            acc[1][0] += a1 * b0; acc[1][1] += a1 * b1; acc[1][2] += a1 * b2; acc[1][3] += a1 * b3;
            acc[2][0] += a2 * b0; acc[2][1] += a2 * b1; acc[2][2] += a2 * b2; acc[2][3] += a2 * b3;
            acc[3][0] += a3 * b0; acc[3][1] += a3 * b1; acc[3][2] += a3 * b2; acc[3][3] += a3 * b3;
        }
        if (tid < CC) {
#pragma unroll 8
            for (int pp = 0; pp < 32; ++pp) cs += lds[pp * 68 + tid];
        }
#pragma unroll
        for (int k = 0; k < 8; ++k) ld[k] = ld2[k];
    }

    float* __restrict__ G = pG + (size_t)blk * 4096;
#pragma unroll
    for (int a = 0; a < 4; ++a)
#pragma unroll
        for (int bb = 0; bb < 4; ++bb)
            G[(4 * i + a) * 64 + (4 * j + bb)] = acc[a][bb];
    if (tid < CC) pS[blk * 64 + tid] = cs;
}

// ---------------------------------------------------------------------------
// Kernel 1b: reduce 10 partials -> covariance -> FULL symmetric W in bf16
// hi/lo split. 40 blocks, 256 threads. (verified in R7, unchanged)
// ---------------------------------------------------------------------------
__global__ __launch_bounds__(256) void k_finalize(const float* __restrict__ pG,
                                                  const float* __restrict__ pS,
                                                  unsigned short* __restrict__ Wh,
                                                  unsigned short* __restrict__ Wl) {
    const int b = blockIdx.x;                    // t*5 + way
    const int t = b / WAY, way = b % WAY;
    const int s0 = (t * 25 + way * SHOT) * 2;

    for (int idx = threadIdx.x; idx < 4096; idx += 256) {
        const int c = idx >> 6, d = idx & 63;
        float g = 0.f, Sc = 0.f, Sd = 0.f;
#pragma unroll
        for (int s = 0; s < SHOT * 2; ++s) {
            g  += pG[(size_t)(s0 + s) * 4096 + idx];
            Sc += pS[(s0 + s) * 64 + c];
            Sd += pS[(s0 + s) * 64 + d];
        }
        const float cov = (g - Sc * Sd * (1.f / NSAMP)) * (1.f / (HW - 1));
        const unsigned short hi = f2bf(cov);
        const unsigned short lo = f2bf(cov - bf2f(hi));
        Wh[(size_t)b * 4096 + idx] = hi;
        Wl[(size_t)b * 4096 + idx] = lo;
    }
}

// ---------------------------------------------------------------------------
// Kernel 1c: per-(t,qi,c) means. 600 blocks, 256 threads.
// Thread (pp = tid&15, c-base = tid>>4): coalesced 64B row segments,
// 16-lane shfl reduction.
// ---------------------------------------------------------------------------
__global__ __launch_bounds__(256) void k_mu(const float* __restrict__ Q,
                                            float* __restrict__ mu) {
    const int b = blockIdx.x;                    // t*75 + qi
    const float* __restrict__ Qb = Q + (size_t)b * CC * HW;
    const int tid = threadIdx.x;
    const int pp = tid & 15;
    const int cb_ = tid >> 4;                    // 0..15
#pragma unroll
    for (int cc = 0; cc < 4; ++cc) {
        const int c = cb_ + cc * 16;
        float s = 0.f;
        for (int p = pp; p < HW; p += 16) s += Qb[(size_t)c * HW + p];
        s += __shfl_xor(s, 1, 64);
        s += __shfl_xor(s, 2, 64);
        s += __shfl_xor(s, 4, 64);
        s += __shfl_xor(s, 8, 64);
        if (pp == 0) mu[b * CC + c] = s * (1.f / HW);
    }
}

// ---------------------------------------------------------------------------
// Kernel 2 v6: one (t,qi,way) per block, 4 waves. Centering + bf16 hi/lo
// split fused in-register from Q (no staging buffers). W-frags resident in
// regs; 7 p-tiles per wave; 24 MFMA per tile; exact-f32 epilogue.
// blockIdx decode keeps a (t,qi)'s 5 way-blocks on ONE XCD, temporally
// adjacent (within 40 consecutive ids) for L2 reuse of the Q slice.
// ---------------------------------------------------------------------------
__global__ __launch_bounds__(256) void k_sim(const float* __restrict__ Q,
                                             const float* __restrict__ mug,
                                             const unsigned short* __restrict__ Wh,
                                             const unsigned short* __restrict__ Wl,
                                             const float* __restrict__ cw,
                                             const float* __restrict__ cb,
                                             float* __restrict__ out) {
    const int gid = blockIdx.x;                  // 0..2999
    const int grp = gid / 40, rem = gid % 40;
    const int w = rem >> 3;                      // 0..4
    const int b = grp * 8 + (rem & 7);           // t*75 + qi   (600 % 8 == 0)
    const int t = b / WQ;
    const int tid = threadIdx.x;
    const int lane = tid & 63;
    const int wid = tid >> 6;                    // 0..3
    const int lm16 = lane & 15;
    const int l16 = lane >> 4;                   // 0..3
    const float lanemask = (l16 == 0) ? 1.f : 0.f;

    __shared__ float muL[CC];
    __shared__ float fin[4];
    if (tid < CC) muL[tid] = mug[b * CC + tid];
    __syncthreads();

    // A-frags: W[row = rt*16 + lm16][k = ks*32 + 8*l16 + i]
    const unsigned short* __restrict__ Wm_h = Wh + (size_t)(t * WAY + w) * 4096;
    const unsigned short* __restrict__ Wm_l = Wl + (size_t)(t * WAY + w) * 4096;
    bf16x8 ah[4][2], al[4][2];
#pragma unroll
    for (int rt = 0; rt < 4; ++rt)
#pragma unroll
        for (int ks = 0; ks < 2; ++ks) {
            const size_t off = (size_t)(rt * 16 + lm16) * 64 + ks * 32 + 8 * l16;
            ah[rt][ks] = __builtin_bit_cast(bf16x8, *(const uint4*)(Wm_h + off));
            al[rt][ks] = __builtin_bit_cast(bf16x8, *(const uint4*)(Wm_l + off));
        }

    const float* __restrict__ Qb = Q + (size_t)b * CC * HW;

    float wayacc = 0.f;
#pragma unroll 1
    for (int k = 0; k < 7; ++k) {
        const int p_l = (wid + 4 * k) * 16 + lm16;
        const int pc = (p_l < HW) ? p_l : (HW - 1);   // clamp; garbage cols masked

        // B-frags built in-register: S[c][p] = Q[c][p] - mu[c], split hi/lo
        bf16x8 bh[2], bl[2];
#pragma unroll
        for (int ks = 0; ks < 2; ++ks) {
            unsigned hp[4], lp[4];
#pragma unroll
            for (int jj = 0; jj < 4; ++jj) {
                const int cA = ks * 32 + 8 * l16 + jj * 2;
                const float v0 = Qb[(size_t)cA * HW + pc] - muL[cA];
                const float v1 = Qb[(size_t)(cA + 1) * HW + pc] - muL[cA + 1];
                const unsigned short h0 = f2bf(v0), h1 = f2bf(v1);
                const unsigned short l0 = f2bf(v0 - bf2f(h0));
                const unsigned short l1 = f2bf(v1 - bf2f(h1));
                hp[jj] = (unsigned)h0 | ((unsigned)h1 << 16);
                lp[jj] = (unsigned)l0 | ((unsigned)l1 << 16);
            }
            bh[ks] = __builtin_bit_cast(bf16x8, make_uint4(hp[0], hp[1], hp[2], hp[3]));
            bl[ks] = __builtin_bit_cast(bf16x8, make_uint4(lp[0], lp[1], lp[2], lp[3]));
        }

        f32x4 acc[4];
#pragma unroll
        for (int rt = 0; rt < 4; ++rt) acc[rt] = (f32x4){0.f, 0.f, 0.f, 0.f};

#pragma unroll
        for (int rt = 0; rt < 4; ++rt)
#pragma unroll
            for (int ks = 0; ks < 2; ++ks) {
                acc[rt] = __builtin_amdgcn_mfma_f32_16x16x32_bf16(ah[rt][ks], bh[ks], acc[rt], 0, 0, 0);
                acc[rt] = __builtin_amdgcn_mfma_f32_16x16x32_bf16(ah[rt][ks], bl[ks], acc[rt], 0, 0, 0);
                acc[rt] = __builtin_amdgcn_mfma_f32_16x16x32_bf16(al[rt][ks], bh[ks], acc[rt], 0, 0, 0);
            }

        // epilogue: simp = sum over this lane's 16 c's of S[c][p] * M[c][p],
        // c = rt*16 + l16*4 + r (measured m89 C/D layout), exact f32 S.
        float simp = 0.f;
#pragma unroll
        for (int rt = 0; rt < 4; ++rt) {
#pragma unroll
            for (int r = 0; r < 4; ++r) {
                const int c = rt * 16 + l16 * 4 + r;
                const float s = Qb[(size_t)c * HW + pc] - muL[c];
                simp += acc[rt][r] * s;
            }
        }
        simp += __shfl_xor(simp, 16, 64);
        simp += __shfl_xor(simp, 32, 64);

        const float cwv = (p_l < HW) ? cw[p_l] : 0.f;
        const float x = (simp >= 0.f) ? simp : NEG * simp;
        wayacc += lanemask * x * cwv;
    }

#pragma unroll
    for (int m = 32; m > 0; m >>= 1) wayacc += __shfl_xor(wayacc, m, 64);
    if (lane == 0) fin[wid] = wayacc;
    __syncthreads();
    if (tid == 0)
        out[(size_t)b * WAY + w] = fin[0] + fin[1] + fin[2] + fin[3] + cb[0];
}

// ---------------------------------------------------------------------------
extern "C" void kernel_launch(void* const* d_in, const int* in_sizes, int n_in,
                              void* d_out, int out_size, void* d_ws, size_t ws_size,
                              hipStream_t stream) {
    const float* q   = (const float*)d_in[0];   // (8,75,64,21,21)
    const float* sup = (const float*)d_in[1];   // (8,25,64,21,21)
    const float* cw  = (const float*)d_in[2];   // (441,)
    const float* cb  = (const float*)d_in[3];   // (1,)
    float* out = (float*)d_out;                  // (8,75,5)

    char* ws = (char*)d_ws;
    float* pG = (float*)ws;                                    // 6,553,600 B
    float* pS = (float*)(ws + 6553600);                        //   102,400 B
    unsigned short* Wh = (unsigned short*)(ws + 6656000);      //   327,680 B
    unsigned short* Wl = (unsigned short*)(ws + 6983680);      //   327,680 B
    float* mu = (float*)(ws + 7311360);                        //   153,600 B
    // total 7,464,960 B

    k_partial<<<TT * 25 * 2, 256, 0, stream>>>(sup, pG, pS);
    k_finalize<<<TT * WAY, 256, 0, stream>>>(pG, pS, Wh, Wl);
    k_mu<<<TT * WQ, 256, 0, stream>>>(q, mu);
    k_sim<<<TT * WQ * WAY, 256, 0, stream>>>(q, mu, Wh, Wl, cw, cb, out);
}